// Round 1
// baseline (1071.144 us; speedup 1.0000x reference)
//
#include <hip/hip_runtime.h>
#include <hip/hip_bf16.h>
#include <stdint.h>

// LSTM fused cell, MI355X gfx950.
// out = [x|h] @ [W_ih|W_hh]^T + b ; gates f,i,s,o ; c' = f*c + i*s ; h' = o*tanh(c')
// Strategy: fp32 -> (bf16 hi, bf16 lo) split, 3-pass bf16 MFMA (hi*hi + hi*lo + lo*hi)
// with fp32 accumulate => ~1e-5 abs accuracy. Gate-grouped N tiling so the whole
// epilogue is register-local per lane (no [B,4H] intermediate in HBM).

typedef float  f32x4  __attribute__((ext_vector_type(4)));
typedef __bf16 bf16x8 __attribute__((ext_vector_type(8)));
typedef unsigned short u16x4 __attribute__((ext_vector_type(4)));

#define B_ROWS 4096
#define HDIM   2048
#define KDIM   4096               // I + H
#define W_ROWS 8192               // 4*H
#define BH     ((size_t)B_ROWS * HDIM)

__device__ __forceinline__ void split_bf16(float f, unsigned short& h, unsigned short& l) {
    __bf16 hb = (__bf16)f;                // RNE truncate fp32->bf16
    float  r  = f - (float)hb;            // exact (Sterbenz)
    __bf16 lb = (__bf16)r;
    h = __builtin_bit_cast(unsigned short, hb);
    l = __builtin_bit_cast(unsigned short, lb);
}

// Pack two [rows,2048] fp32 sources into concatenated [rows,4096] bf16 hi/lo planes.
__global__ void pack_split_kernel(const float* __restrict__ s0,
                                  const float* __restrict__ s1,
                                  unsigned short* __restrict__ hi,
                                  unsigned short* __restrict__ lo,
                                  int nvec) {
    for (int idx = blockIdx.x * blockDim.x + threadIdx.x; idx < nvec;
         idx += gridDim.x * blockDim.x) {
        int e = idx << 2;                 // element index, row length 4096
        int r = e >> 12;
        int k = e & 4095;
        const float* src = (k < 2048) ? (s0 + ((size_t)r << 11) + k)
                                      : (s1 + ((size_t)r << 11) + (k - 2048));
        f32x4 v = *reinterpret_cast<const f32x4*>(src);
        u16x4 vh, vl;
#pragma unroll
        for (int j = 0; j < 4; ++j) {
            unsigned short hh, ll;
            split_bf16(v[j], hh, ll);
            vh[j] = hh; vl[j] = ll;
        }
        *reinterpret_cast<u16x4*>(hi + e) = vh;
        *reinterpret_cast<u16x4*>(lo + e) = vl;
    }
}

__device__ __forceinline__ void async16(const unsigned short* g, unsigned short* s) {
    __builtin_amdgcn_global_load_lds(
        (const __attribute__((address_space(1))) unsigned int*)g,
        (__attribute__((address_space(3))) unsigned int*)s, 16, 0, 0);
}

__device__ __forceinline__ float sigmoid_f(float x) {
    return 1.0f / (1.0f + __expf(-x));
}
__device__ __forceinline__ float tanh_f(float x) {
    float t = __expf(-2.0f * fabsf(x));
    return copysignf((1.0f - t) / (1.0f + t), x);
}

// Block tile: 128 B-rows x (32 h-cols * 4 gates = 128 W-rows), BK=64.
// 4 waves in 2x2. Wave's 64 cols = 4 fragments of 16 = the 4 gates of 16 h-cols.
__global__ __launch_bounds__(256, 2) void lstm_fused_kernel(
    const unsigned short* __restrict__ Ah, const unsigned short* __restrict__ Al,
    const unsigned short* __restrict__ Wh, const unsigned short* __restrict__ Wl,
    const float* __restrict__ bias, const float* __restrict__ cin,
    float* __restrict__ out)
{
    __shared__ __align__(16) unsigned short sAh[128 * 64];
    __shared__ __align__(16) unsigned short sAl[128 * 64];
    __shared__ __align__(16) unsigned short sWh[128 * 64];
    __shared__ __align__(16) unsigned short sWl[128 * 64];

    const int tid  = threadIdx.x;
    const int wid  = tid >> 6;
    const int lane = tid & 63;
    const int wm   = wid >> 1;
    const int wn   = wid & 1;
    const int row0  = blockIdx.y * 128;   // batch rows
    const int hcol0 = blockIdx.x * 32;    // h columns

    const int rsub = lane >> 3;           // staging: row-within-8-chunk
    const int kyo  = (lane & 7) << 3;     // staging: k element offset (8 bf16 = 16B)

    f32x4 acc[4][4];
#pragma unroll
    for (int m = 0; m < 4; ++m)
#pragma unroll
        for (int n = 0; n < 4; ++n)
            acc[m][n] = (f32x4)0.0f;

    // Per-lane invariant staging offsets. Local row j in [0,128):
    //   A global row = row0 + j
    //   W global row = gate(j)*2048 + hcol0 + (j>>6)*16 + (j&15), gate=(j>>4)&3
    size_t aoff[4], woff[4];
    int lbase[4];
#pragma unroll
    for (int it = 0; it < 4; ++it) {
        int lr = wid * 32 + it * 8;       // chunk start local row (wave-uniform)
        int j  = lr + rsub;
        aoff[it] = (size_t)(row0 + j) * KDIM + kyo;
        int wrow = (((j >> 4) & 3) << 11) + hcol0 + ((j >> 6) << 4) + (j & 15);
        woff[it] = (size_t)wrow * KDIM + kyo;
        lbase[it] = lr * 64;              // ushort offset of chunk base (wave-uniform)
    }

    for (int k0 = 0; k0 < KDIM; k0 += 64) {
#pragma unroll
        for (int it = 0; it < 4; ++it) {
            async16(Ah + aoff[it] + k0, &sAh[lbase[it]]);
            async16(Al + aoff[it] + k0, &sAl[lbase[it]]);
            async16(Wh + woff[it] + k0, &sWh[lbase[it]]);
            async16(Wl + woff[it] + k0, &sWl[lbase[it]]);
        }
        __syncthreads();   // compiler emits vmcnt(0) drain before barrier

        const int arow = (wm << 6) + (lane & 15);
        const int brow = (wn << 6) + (lane & 15);
#pragma unroll
        for (int kk = 0; kk < 64; kk += 32) {
            const int kof = kk + ((lane >> 4) << 3);
            bf16x8 ah[4], alo[4], bh[4], blo[4];
#pragma unroll
            for (int m = 0; m < 4; ++m) {
                ah[m]  = *reinterpret_cast<const bf16x8*>(&sAh[(arow + m * 16) * 64 + kof]);
                alo[m] = *reinterpret_cast<const bf16x8*>(&sAl[(arow + m * 16) * 64 + kof]);
            }
#pragma unroll
            for (int n = 0; n < 4; ++n) {
                bh[n]  = *reinterpret_cast<const bf16x8*>(&sWh[(brow + n * 16) * 64 + kof]);
                blo[n] = *reinterpret_cast<const bf16x8*>(&sWl[(brow + n * 16) * 64 + kof]);
            }
            // pass 1: hi*hi
#pragma unroll
            for (int m = 0; m < 4; ++m)
#pragma unroll
                for (int n = 0; n < 4; ++n)
                    acc[m][n] = __builtin_amdgcn_mfma_f32_16x16x32_bf16(ah[m], bh[n], acc[m][n], 0, 0, 0);
            // pass 2: hi*lo
#pragma unroll
            for (int m = 0; m < 4; ++m)
#pragma unroll
                for (int n = 0; n < 4; ++n)
                    acc[m][n] = __builtin_amdgcn_mfma_f32_16x16x32_bf16(ah[m], blo[n], acc[m][n], 0, 0, 0);
            // pass 3: lo*hi
#pragma unroll
            for (int m = 0; m < 4; ++m)
#pragma unroll
                for (int n = 0; n < 4; ++n)
                    acc[m][n] = __builtin_amdgcn_mfma_f32_16x16x32_bf16(alo[m], bh[n], acc[m][n], 0, 0, 0);
        }
        __syncthreads();
    }

    // Epilogue: per lane, acc[m][gate][r] are the 4 gate pre-activations of
    // (row = row0+wm*64+m*16+(lane>>4)*4+r, hcol = hcol0+wn*16+(lane&15)).
    const int hcol = hcol0 + (wn << 4) + (lane & 15);
    const float bf_ = bias[hcol];
    const float bi_ = bias[HDIM + hcol];
    const float bs_ = bias[2 * HDIM + hcol];
    const float bo_ = bias[3 * HDIM + hcol];
    const int rbase = row0 + (wm << 6) + ((lane >> 4) << 2);
#pragma unroll
    for (int m = 0; m < 4; ++m) {
#pragma unroll
        for (int r = 0; r < 4; ++r) {
            int grow = rbase + m * 16 + r;
            float gf = sigmoid_f(acc[m][0][r] + bf_);
            float gi = sigmoid_f(acc[m][1][r] + bi_);
            float gs = tanh_f   (acc[m][2][r] + bs_);
            float go = sigmoid_f(acc[m][3][r] + bo_);
            size_t o0 = (size_t)grow * HDIM + hcol;
            float cn = gf * cin[o0] + gi * gs;
            float hn = go * tanh_f(cn);
            out[o0]          = hn;
            out[BH + o0]     = cn;
            out[2 * BH + o0] = go;
        }
    }
}

extern "C" void kernel_launch(void* const* d_in, const int* in_sizes, int n_in,
                              void* d_out, int out_size, void* d_ws, size_t ws_size,
                              hipStream_t stream) {
    const float* x    = (const float*)d_in[0];
    const float* h    = (const float*)d_in[1];
    const float* c    = (const float*)d_in[2];
    // d_in[3] ("o") is unused by the reference computation.
    const float* w_ih = (const float*)d_in[4];
    const float* w_hh = (const float*)d_in[5];
    const float* b    = (const float*)d_in[6];
    float* out = (float*)d_out;

    // Workspace: A(hi,lo) [4096,4096] + W(hi,lo) [8192,4096] bf16 => 201.3 MB
    unsigned short* Ah = (unsigned short*)d_ws;
    unsigned short* Al = Ah + (size_t)B_ROWS * KDIM;
    unsigned short* Wh = Al + (size_t)B_ROWS * KDIM;
    unsigned short* Wl = Wh + (size_t)W_ROWS * KDIM;

    const int nvA = (int)((size_t)B_ROWS * KDIM / 4);   // 4,194,304 float4 groups
    const int nvW = (int)((size_t)W_ROWS * KDIM / 4);   // 8,388,608

    pack_split_kernel<<<2048, 256, 0, stream>>>(x,    h,    Ah, Al, nvA);
    pack_split_kernel<<<2048, 256, 0, stream>>>(w_ih, w_hh, Wh, Wl, nvW);

    dim3 grid(HDIM / 32, B_ROWS / 128);  // (64, 32)
    lstm_fused_kernel<<<grid, 256, 0, stream>>>(Ah, Al, Wh, Wl, b, c, out);
}

// Round 2
// 948.020 us; speedup vs baseline: 1.1299x; 1.1299x over previous
//
#include <hip/hip_runtime.h>
#include <hip/hip_bf16.h>
#include <stdint.h>

// LSTM fused cell, MI355X gfx950.
// out = [x|h] @ [W_ih|W_hh]^T + b ; gates f,i,s,o ; c' = f*c + i*s ; h' = o*tanh(c')
// Strategy: fp32 -> (bf16 hi, bf16 lo) split, 3-pass bf16 MFMA (hi*hi + hi*lo + lo*hi)
// with fp32 accumulate. Gate-grouped N tiling => register-local epilogue.
// R2: T2 XOR-swizzle on LDS tiles (16-way bank conflict fix, rule-21 compliant:
//     pre-swizzled GLOBAL source + swizzled ds_read, LDS dest stays linear).

typedef float  f32x4  __attribute__((ext_vector_type(4)));
typedef __bf16 bf16x8 __attribute__((ext_vector_type(8)));
typedef unsigned short u16x8 __attribute__((ext_vector_type(8)));

#define B_ROWS 4096
#define HDIM   2048
#define KDIM   4096               // I + H
#define W_ROWS 8192               // 4*H
#define BH     ((size_t)B_ROWS * HDIM)

__device__ __forceinline__ void split_bf16(float f, unsigned short& h, unsigned short& l) {
    __bf16 hb = (__bf16)f;                // RNE fp32->bf16
    float  r  = f - (float)hb;            // exact residual
    __bf16 lb = (__bf16)r;
    h = __builtin_bit_cast(unsigned short, hb);
    l = __builtin_bit_cast(unsigned short, lb);
}

// Pack two [rows,2048] fp32 sources into concatenated [rows,4096] bf16 hi/lo planes.
// 8 floats per thread; 16B stores per plane.
__global__ void pack_split_kernel(const float* __restrict__ s0,
                                  const float* __restrict__ s1,
                                  unsigned short* __restrict__ hi,
                                  unsigned short* __restrict__ lo,
                                  int nvec) {
    for (int idx = blockIdx.x * blockDim.x + threadIdx.x; idx < nvec;
         idx += gridDim.x * blockDim.x) {
        int e = idx << 3;                 // element index, row length 4096
        int r = e >> 12;
        int k = e & 4095;
        const float* src = (k < 2048) ? (s0 + ((size_t)r << 11) + k)
                                      : (s1 + ((size_t)r << 11) + (k - 2048));
        f32x4 v0 = *reinterpret_cast<const f32x4*>(src);
        f32x4 v1 = *reinterpret_cast<const f32x4*>(src + 4);
        u16x8 vh, vl;
#pragma unroll
        for (int j = 0; j < 4; ++j) {
            unsigned short hh, ll;
            split_bf16(v0[j], hh, ll);
            vh[j] = hh; vl[j] = ll;
            split_bf16(v1[j], hh, ll);
            vh[j + 4] = hh; vl[j + 4] = ll;
        }
        *reinterpret_cast<u16x8*>(hi + e) = vh;
        *reinterpret_cast<u16x8*>(lo + e) = vl;
    }
}

__device__ __forceinline__ void async16(const unsigned short* g, unsigned short* s) {
    __builtin_amdgcn_global_load_lds(
        (const __attribute__((address_space(1))) unsigned int*)g,
        (__attribute__((address_space(3))) unsigned int*)s, 16, 0, 0);
}

__device__ __forceinline__ float sigmoid_f(float x) {
    return 1.0f / (1.0f + __expf(-x));
}
__device__ __forceinline__ float tanh_f(float x) {
    float t = __expf(-2.0f * fabsf(x));
    return copysignf((1.0f - t) / (1.0f + t), x);
}

// Block tile: 128 B-rows x (32 h-cols * 4 gates = 128 W-rows), BK=64.
// 4 waves in 2x2. Wave's 64 cols = 4 fragments of 16 = the 4 gates of 16 h-cols.
//
// LDS layout per tile: [row j][slot g] of 16B groups, g in 0..7.
// SWIZZLE: slot (j,g) holds global k-group (g ^ (j&7)). Writers (global_load_lds,
// lane l -> row l>>3, slot l&7) therefore fetch global k-group (l&7)^(l>>3).
// Readers wanting (row j, k-group kg) read slot kg ^ (j&7). For every fragment
// row here, j&7 == lane&7, so the XOR term is a per-lane constant.
__global__ __launch_bounds__(256, 2) void lstm_fused_kernel(
    const unsigned short* __restrict__ Ah, const unsigned short* __restrict__ Al,
    const unsigned short* __restrict__ Wh, const unsigned short* __restrict__ Wl,
    const float* __restrict__ bias, const float* __restrict__ cin,
    float* __restrict__ out)
{
    __shared__ __align__(16) unsigned short sAh[128 * 64];
    __shared__ __align__(16) unsigned short sAl[128 * 64];
    __shared__ __align__(16) unsigned short sWh[128 * 64];
    __shared__ __align__(16) unsigned short sWl[128 * 64];

    const int tid  = threadIdx.x;
    const int wid  = tid >> 6;
    const int lane = tid & 63;
    const int wm   = wid >> 1;
    const int wn   = wid & 1;
    const int row0  = blockIdx.y * 128;   // batch rows
    const int hcol0 = blockIdx.x * 32;    // h columns

    const int rsub = lane >> 3;                      // staging: row within 8-chunk
    const int kswz = (((lane & 7) ^ rsub) << 3);     // swizzled k element offset

    f32x4 acc[4][4];
#pragma unroll
    for (int m = 0; m < 4; ++m)
#pragma unroll
        for (int n = 0; n < 4; ++n)
            acc[m][n] = (f32x4)0.0f;

    // Per-lane invariant staging offsets. Local row j in [0,128):
    //   A global row = row0 + j
    //   W global row = gate(j)*2048 + hcol0 + (j>>6)*16 + (j&15), gate=(j>>4)&3
    size_t aoff[4], woff[4];
    int lbase[4];
#pragma unroll
    for (int it = 0; it < 4; ++it) {
        int lr = wid * 32 + it * 8;       // chunk start local row (wave-uniform)
        int j  = lr + rsub;
        aoff[it] = (size_t)(row0 + j) * KDIM + kswz;
        int wrow = (((j >> 4) & 3) << 11) + hcol0 + ((j >> 6) << 4) + (j & 15);
        woff[it] = (size_t)wrow * KDIM + kswz;
        lbase[it] = lr * 64;              // ushort offset of chunk base (wave-uniform)
    }

    const int arow = (wm << 6) + (lane & 15);
    const int brow = (wn << 6) + (lane & 15);
    const int r7   = lane & 7;            // == (fragment row)&7 for all m/n

    for (int k0 = 0; k0 < KDIM; k0 += 64) {
#pragma unroll
        for (int it = 0; it < 4; ++it) {
            async16(Ah + aoff[it] + k0, &sAh[lbase[it]]);
            async16(Al + aoff[it] + k0, &sAl[lbase[it]]);
            async16(Wh + woff[it] + k0, &sWh[lbase[it]]);
            async16(Wl + woff[it] + k0, &sWl[lbase[it]]);
        }
        __syncthreads();   // compiler emits vmcnt(0) drain before barrier

#pragma unroll
        for (int kk = 0; kk < 64; kk += 32) {
            const int kg  = (kk >> 3) + (lane >> 4);     // k-group 0..7
            const int sof = ((kg ^ r7) << 3);            // swizzled ushort offset
            bf16x8 ah[4], alo[4], bh[4], blo[4];
#pragma unroll
            for (int m = 0; m < 4; ++m) {
                ah[m]  = *reinterpret_cast<const bf16x8*>(&sAh[(arow + m * 16) * 64 + sof]);
                alo[m] = *reinterpret_cast<const bf16x8*>(&sAl[(arow + m * 16) * 64 + sof]);
            }
#pragma unroll
            for (int n = 0; n < 4; ++n) {
                bh[n]  = *reinterpret_cast<const bf16x8*>(&sWh[(brow + n * 16) * 64 + sof]);
                blo[n] = *reinterpret_cast<const bf16x8*>(&sWl[(brow + n * 16) * 64 + sof]);
            }
            // pass 1: hi*hi
#pragma unroll
            for (int m = 0; m < 4; ++m)
#pragma unroll
                for (int n = 0; n < 4; ++n)
                    acc[m][n] = __builtin_amdgcn_mfma_f32_16x16x32_bf16(ah[m], bh[n], acc[m][n], 0, 0, 0);
            // pass 2: hi*lo
#pragma unroll
            for (int m = 0; m < 4; ++m)
#pragma unroll
                for (int n = 0; n < 4; ++n)
                    acc[m][n] = __builtin_amdgcn_mfma_f32_16x16x32_bf16(ah[m], blo[n], acc[m][n], 0, 0, 0);
            // pass 3: lo*hi
#pragma unroll
            for (int m = 0; m < 4; ++m)
#pragma unroll
                for (int n = 0; n < 4; ++n)
                    acc[m][n] = __builtin_amdgcn_mfma_f32_16x16x32_bf16(alo[m], bh[n], acc[m][n], 0, 0, 0);
        }
        __syncthreads();
    }

    // Epilogue: per lane, acc[m][gate][r] are the 4 gate pre-activations of
    // (row = row0+wm*64+m*16+(lane>>4)*4+r, hcol = hcol0+wn*16+(lane&15)).
    const int hcol = hcol0 + (wn << 4) + (lane & 15);
    const float bf_ = bias[hcol];
    const float bi_ = bias[HDIM + hcol];
    const float bs_ = bias[2 * HDIM + hcol];
    const float bo_ = bias[3 * HDIM + hcol];
    const int rbase = row0 + (wm << 6) + ((lane >> 4) << 2);
#pragma unroll
    for (int m = 0; m < 4; ++m) {
#pragma unroll
        for (int r = 0; r < 4; ++r) {
            int grow = rbase + m * 16 + r;
            float gf = sigmoid_f(acc[m][0][r] + bf_);
            float gi = sigmoid_f(acc[m][1][r] + bi_);
            float gs = tanh_f   (acc[m][2][r] + bs_);
            float go = sigmoid_f(acc[m][3][r] + bo_);
            size_t o0 = (size_t)grow * HDIM + hcol;
            float cn = gf * cin[o0] + gi * gs;
            float hn = go * tanh_f(cn);
            out[o0]          = hn;
            out[BH + o0]     = cn;
            out[2 * BH + o0] = go;
        }
    }
}

extern "C" void kernel_launch(void* const* d_in, const int* in_sizes, int n_in,
                              void* d_out, int out_size, void* d_ws, size_t ws_size,
                              hipStream_t stream) {
    const float* x    = (const float*)d_in[0];
    const float* h    = (const float*)d_in[1];
    const float* c    = (const float*)d_in[2];
    // d_in[3] ("o") is unused by the reference computation.
    const float* w_ih = (const float*)d_in[4];
    const float* w_hh = (const float*)d_in[5];
    const float* b    = (const float*)d_in[6];
    float* out = (float*)d_out;

    // Workspace: A(hi,lo) [4096,4096] + W(hi,lo) [8192,4096] bf16 => 201.3 MB
    unsigned short* Ah = (unsigned short*)d_ws;
    unsigned short* Al = Ah + (size_t)B_ROWS * KDIM;
    unsigned short* Wh = Al + (size_t)B_ROWS * KDIM;
    unsigned short* Wl = Wh + (size_t)W_ROWS * KDIM;

    const int nvA = (int)((size_t)B_ROWS * KDIM / 8);   // 2,097,152 8-float groups
    const int nvW = (int)((size_t)W_ROWS * KDIM / 8);   // 4,194,304

    pack_split_kernel<<<4096, 256, 0, stream>>>(x,    h,    Ah, Al, nvA);
    pack_split_kernel<<<4096, 256, 0, stream>>>(w_ih, w_hh, Wh, Wl, nvW);

    dim3 grid(HDIM / 32, B_ROWS / 128);  // (64, 32)
    lstm_fused_kernel<<<grid, 256, 0, stream>>>(Ah, Al, Wh, Wl, b, c, out);
}